// Round 10
// baseline (35.064 us; speedup 1.0000x reference)
//
#include <hip/hip_runtime.h>
#include <math.h>

// DISTANA fused prediction-kernel step.
// B=128, N=4096, IN=9, PRE=4, CELLS=16, OUT=9.
// Outputs: y (B,N,9) | new_h (B,N,16) | new_cell (B,N,16), f32 concat.
//
// R10 = R9 (quad-cooperative, DPP butterflies, 31.4us) + 2 tiles/block with
// 1-deep register prefetch: tile-1's x/h/c (12 floats) issued before tile-0's
// ~400-cyc compute chain -> HBM latency hidden under compute, not just under
// wave TLP. Grid 4096 (2 block generations/CU). Weights staged once.
// Prefetch state is small (R3/R5's spill came from 2 FULL node states).

#define NNODES 524288
#define IN_DIM 9
#define CELLS 16
#define OUT_DIM 9
#define TPB 256
#define NPT 64               // nodes per tile (4 lanes/node, 256 threads)
#define TILES 2              // tiles per block
#define NPB (NPT * TILES)    // 128 nodes per block
#define NBLK (NNODES / NPB)  // 4096, divisible by 8
#define NXCD 8

typedef float f32x4 __attribute__((ext_vector_type(4)));

__device__ __forceinline__ float fast_rcp(float x) {
    return __builtin_amdgcn_rcpf(x);
}

__device__ __forceinline__ float tanh_nc(float x) {
    // no clamp: caller guarantees |x| << 44 (exp argument < 88, no overflow)
    float e = __expf(2.f * x);
    return (e - 1.f) * fast_rcp(e + 1.f);
}

__device__ __forceinline__ float fast_tanh(float x) {
    return tanh_nc(fminf(fmaxf(x, -15.f), 15.f));
}

// quad butterfly sum via DPP quad_perm: xor1 = [1,0,3,2] = 0xB1,
// xor2 = [2,3,0,1] = 0x4E. Pure VALU (mov_dpp + add), no LDS pipe.
__device__ __forceinline__ float qsum(float v) {
    int a = __builtin_amdgcn_update_dpp(0, __float_as_int(v), 0xB1, 0xF, 0xF, true);
    v += __int_as_float(a);
    int b = __builtin_amdgcn_update_dpp(0, __float_as_int(v), 0x4E, 0xF, 0xF, true);
    v += __int_as_float(b);
    return v;
}

struct NodeIn { f32x4 xl, h, c; };

__device__ __forceinline__ NodeIn load_node(
    const float* __restrict__ input, const float* __restrict__ old_h,
    const float* __restrict__ old_cell, int node, int sub)
{
    NodeIn r;
    const float* xp = input + (size_t)node * IN_DIM;
    r.xl = (f32x4){0.f, 0.f, 0.f, 0.f};
    if (sub == 0)      { r.xl[0] = xp[0]; r.xl[1] = xp[1]; r.xl[2] = xp[2]; r.xl[3] = xp[3]; }
    else if (sub == 1) { r.xl[0] = xp[4]; r.xl[1] = xp[5]; r.xl[2] = xp[6]; r.xl[3] = xp[7]; }
    else if (sub == 2) { r.xl[0] = xp[8]; }
    r.h = *(const f32x4*)(old_h    + (size_t)node * CELLS + sub * 4);
    r.c = *(const f32x4*)(old_cell + (size_t)node * CELLS + sub * 4);
    return r;
}

__device__ __forceinline__ void compute_store_node(
    const NodeIn& in, const float* sWpre, const float* sWl, const float* sWp,
    float* __restrict__ y, float* __restrict__ new_h, float* __restrict__ new_cell,
    int node, int sub)
{
    // pre = tanh(x @ W_pre): per-lane partial dot + DPP butterfly
    float pre[4];
    #pragma unroll
    for (int p = 0; p < 4; ++p) {
        float s = 0.f;
        #pragma unroll
        for (int k = 0; k < 4; ++k)
            s = fmaf(in.xl[k], sWpre[(sub * 4 + k) * 4 + p], s);
        pre[p] = fast_tanh(qsum(s));      // x unbounded -> keep clamp
    }

    // CIFG cell: this lane owns cells sub*4 .. sub*4+3
    f32x4 nh, nc;
    #pragma unroll
    for (int j = 0; j < 4; ++j) {
        const int cc = sub * 4 + j;
        float s = in.h[j];
        #pragma unroll
        for (int p = 0; p < 4; ++p)
            s = fmaf(pre[p], sWl[p * CELLS + cc], s);
        float e  = __expf(s);                 // e^net, |net|<=7
        float e2 = e * e;
        float a  = 1.f + e;
        float b  = 1.f + e2;
        float r  = fast_rcp(a * b);           // one rcp for both gates
        float ig = e * b * r;                 // sigmoid(net)
        float g  = (e2 - 1.f) * a * r;        // tanh(net)
        float v  = fmaf(ig, g - in.c[j], in.c[j]);
        nc[j] = v;
        nh[j] = tanh_nc(v);                   // |v| <= ~6
    }
    *(f32x4*)(new_h    + (size_t)node * CELLS + sub * 4) = nh;
    *(f32x4*)(new_cell + (size_t)node * CELLS + sub * 4) = nc;

    // y = tanh(new_h @ W_post): partial over own 4 cells + butterfly
    float py[OUT_DIM];
    #pragma unroll
    for (int o = 0; o < OUT_DIM; ++o) {
        float s = 0.f;
        #pragma unroll
        for (int j = 0; j < 4; ++j)
            s = fmaf(nh[j], sWp[(sub * 4 + j) * OUT_DIM + o], s);
        py[o] = qsum(s);                  // |y pre-act| <= 4
    }
    float* yo = y + (size_t)node * OUT_DIM;
    if (sub == 0) {
        yo[0] = tanh_nc(py[0]); yo[1] = tanh_nc(py[1]); yo[2] = tanh_nc(py[2]);
    } else if (sub == 1) {
        yo[3] = tanh_nc(py[3]); yo[4] = tanh_nc(py[4]); yo[5] = tanh_nc(py[5]);
    } else if (sub == 2) {
        yo[6] = tanh_nc(py[6]); yo[7] = tanh_nc(py[7]); yo[8] = tanh_nc(py[8]);
    }
}

__global__ __launch_bounds__(TPB) void distana_quad_kernel(
    const float* __restrict__ input,      // (B,N,9)
    const float* __restrict__ w_pre,      // (9,4)
    const float* __restrict__ w_lstm,     // (4,16)
    const float* __restrict__ w_post,     // (16,9)
    const float* __restrict__ old_h,      // (B,N,16)
    const float* __restrict__ old_cell,   // (B,N,16)
    float* __restrict__ y,                // (B,N,9)
    float* __restrict__ new_h,            // (B,N,16)
    float* __restrict__ new_cell)         // (B,N,16)
{
    __shared__ float sWpre[64];   // (16 rows x 4), rows 9..15 zeroed
    __shared__ float sWl[64];     // (4,16)
    __shared__ float sWp[144];    // (16,9)

    const int t   = threadIdx.x;
    const int bid = blockIdx.x;
    // bijective XCD swizzle: contiguous tile range per XCD (4096 % 8 == 0)
    const int swz  = (bid & (NXCD - 1)) * (NBLK / NXCD) + (bid >> 3);
    const int quad = t >> 2;
    const int sub  = t & 3;
    const int node0 = swz * NPB + quad;           // tile 0
    const int node1 = node0 + NPT;                // tile 1 (contiguous)

    // ---- weight staging ----
    if (t < 64)  sWpre[t] = (t < 36) ? w_pre[t] : 0.f;
    if (t < 64)  sWl[t]   = w_lstm[t];
    if (t < 144) sWp[t]   = w_post[t];

    // ---- tile-0 loads (in flight across the barrier) ----
    NodeIn n0 = load_node(input, old_h, old_cell, node0, sub);

    __syncthreads();

    // ---- issue tile-1 loads BEFORE tile-0 compute: latency hides under
    //      tile-0's ~400-cycle chain ----
    NodeIn n1 = load_node(input, old_h, old_cell, node1, sub);

    compute_store_node(n0, sWpre, sWl, sWp, y, new_h, new_cell, node0, sub);
    compute_store_node(n1, sWpre, sWl, sWp, y, new_h, new_cell, node1, sub);
}

extern "C" void kernel_launch(void* const* d_in, const int* in_sizes, int n_in,
                              void* d_out, int out_size, void* d_ws, size_t ws_size,
                              hipStream_t stream) {
    const float* input    = (const float*)d_in[0];  // (B,N,9,1)
    const float* w_pre    = (const float*)d_in[1];  // (9,4)
    const float* w_lstm   = (const float*)d_in[2];  // (4,16)
    const float* w_post   = (const float*)d_in[3];  // (16,9)
    const float* old_h    = (const float*)d_in[4];  // (B,N,16)
    const float* old_cell = (const float*)d_in[5];  // (B,N,16)

    float* out = (float*)d_out;
    float* yp       = out;                                    // B*N*9
    float* new_h    = out + (size_t)NNODES * OUT_DIM;         // B*N*16
    float* new_cell = new_h + (size_t)NNODES * CELLS;         // B*N*16

    dim3 grid(NBLK), block(TPB);
    distana_quad_kernel<<<grid, block, 0, stream>>>(
        input, w_pre, w_lstm, w_post, old_h, old_cell, yp, new_h, new_cell);
}

// Round 11
// 31.573 us; speedup vs baseline: 1.1106x; 1.1106x over previous
//
#include <hip/hip_runtime.h>
#include <math.h>

// DISTANA fused prediction-kernel step.
// B=128, N=4096, IN=9, PRE=4, CELLS=16, OUT=9.
// Outputs: y (B,N,9) | new_h (B,N,16) | new_cell (B,N,16), f32 concat.
//
// R11 = R9 (quad-cooperative, DPP butterflies, 31.4us — best) with the
// 4-way-divergent x-load/y-store replaced by strided lane ownership:
//  - lane sub owns x rows {sub, sub+4, 8 if sub==0}: 3 load instructions
//    (2 uniform + 1 masked) instead of 9 divergence-masked scalar loads
//    at the head of the dependent chain; pre-phase 12 FMAs instead of 16.
//  - y outputs {sub, sub+4, 8 if sub==0}: balanced 3/2/2/2 store, constant
//    indices in each branch (no runtime-indexed register arrays).
// Block-fattening axis abandoned: R3/R5 spilled, R6 neutral, R10 -12%.

#define NNODES 524288
#define IN_DIM 9
#define CELLS 16
#define OUT_DIM 9
#define TPB 256
#define NPB 64               // nodes per block (4 lanes/node)
#define NBLK (NNODES / NPB)  // 8192, divisible by 8
#define NXCD 8

typedef float f32x4 __attribute__((ext_vector_type(4)));

__device__ __forceinline__ float fast_rcp(float x) {
    return __builtin_amdgcn_rcpf(x);
}

__device__ __forceinline__ float tanh_nc(float x) {
    // no clamp: caller guarantees |x| << 44 (exp argument < 88, no overflow)
    float e = __expf(2.f * x);
    return (e - 1.f) * fast_rcp(e + 1.f);
}

__device__ __forceinline__ float fast_tanh(float x) {
    return tanh_nc(fminf(fmaxf(x, -15.f), 15.f));
}

// quad butterfly sum via DPP quad_perm: xor1 = [1,0,3,2] = 0xB1,
// xor2 = [2,3,0,1] = 0x4E. Pure VALU (mov_dpp + add), no LDS pipe.
__device__ __forceinline__ float qsum(float v) {
    int a = __builtin_amdgcn_update_dpp(0, __float_as_int(v), 0xB1, 0xF, 0xF, true);
    v += __int_as_float(a);
    int b = __builtin_amdgcn_update_dpp(0, __float_as_int(v), 0x4E, 0xF, 0xF, true);
    v += __int_as_float(b);
    return v;
}

__global__ __launch_bounds__(TPB) void distana_quad_kernel(
    const float* __restrict__ input,      // (B,N,9)
    const float* __restrict__ w_pre,      // (9,4)
    const float* __restrict__ w_lstm,     // (4,16)
    const float* __restrict__ w_post,     // (16,9)
    const float* __restrict__ old_h,      // (B,N,16)
    const float* __restrict__ old_cell,   // (B,N,16)
    float* __restrict__ y,                // (B,N,9)
    float* __restrict__ new_h,            // (B,N,16)
    float* __restrict__ new_cell)         // (B,N,16)
{
    __shared__ float sWpre[36];   // (9,4)
    __shared__ float sWl[64];     // (4,16)
    __shared__ float sWp[144];    // (16,9)

    const int t   = threadIdx.x;
    const int bid = blockIdx.x;
    // bijective XCD swizzle: contiguous tile range per XCD (8192 % 8 == 0)
    const int swz  = (bid & (NXCD - 1)) * (NBLK / NXCD) + (bid >> 3);
    const int node = swz * NPB + (t >> 2);
    const int sub  = t & 3;

    // ---- weight loads first (they gate the barrier; x/h/c stay in flight) ----
    if (t < 36)  sWpre[t] = w_pre[t];
    if (t < 64)  sWl[t]   = w_lstm[t];
    if (t < 144) sWp[t]   = w_post[t];

    // ---- x first (deepest dependency): strided lane ownership, 3 loads ----
    // lane sub holds x[sub], x[sub+4], and (sub==0) x[8]
    const float* xp = input + (size_t)node * IN_DIM;
    float x0 = xp[sub];
    float x1 = xp[sub + 4];
    float x2 = (sub == 0) ? xp[8] : 0.f;

    const float* hp = old_h    + (size_t)node * CELLS + sub * 4;
    const float* cp = old_cell + (size_t)node * CELLS + sub * 4;
    f32x4 h = *(const f32x4*)hp;          // wave: 16 nodes x 64B contiguous
    f32x4 c = *(const f32x4*)cp;

    __syncthreads();

    // ---- pre = tanh(x @ W_pre): 3-row partial dot + DPP butterfly ----
    float pre[4];
    #pragma unroll
    for (int p = 0; p < 4; ++p) {
        float s = x0 * sWpre[sub * 4 + p];
        s = fmaf(x1, sWpre[(sub + 4) * 4 + p], s);
        s = fmaf(x2, sWpre[32 + p], s);   // row 8 (x2==0 for sub!=0)
        pre[p] = fast_tanh(qsum(s));      // x unbounded -> keep clamp
    }

    // ---- CIFG cell: this lane owns cells sub*4 .. sub*4+3 ----
    // net = oh + pre.w: |oh|<~6, |pre.w|<=1 -> |net|<=7, exp safe unclamped
    f32x4 nh, nc;
    #pragma unroll
    for (int j = 0; j < 4; ++j) {
        const int cc = sub * 4 + j;
        float s = h[j];
        #pragma unroll
        for (int p = 0; p < 4; ++p)
            s = fmaf(pre[p], sWl[p * CELLS + cc], s);
        float e  = __expf(s);                 // e^net
        float e2 = e * e;                     // e^{2 net}
        float a  = 1.f + e;
        float b  = 1.f + e2;
        float r  = fast_rcp(a * b);           // one rcp for both gates
        float ig = e * b * r;                 // sigmoid(net)
        float g  = (e2 - 1.f) * a * r;        // tanh(net)
        float v  = fmaf(ig, g - c[j], c[j]);  // (1-i)*oc + i*g
        nc[j] = v;
        nh[j] = tanh_nc(v);                   // |v| <= max(|oc|,1) <= ~6
    }
    *(f32x4*)(new_h    + (size_t)node * CELLS + sub * 4) = nh;
    *(f32x4*)(new_cell + (size_t)node * CELLS + sub * 4) = nc;

    // ---- y = tanh(new_h @ W_post): partial over own 4 cells + butterfly ----
    float py[OUT_DIM];
    #pragma unroll
    for (int o = 0; o < OUT_DIM; ++o) {
        float s = 0.f;
        #pragma unroll
        for (int j = 0; j < 4; ++j)
            s = fmaf(nh[j], sWp[(sub * 4 + j) * OUT_DIM + o], s);
        py[o] = qsum(s);                  // |y pre-act| <= 16*0.25 = 4
    }
    // balanced 3/2/2/2 store, constant indices (no runtime-indexed arrays)
    float* yo = y + (size_t)node * OUT_DIM;
    if (sub == 0) {
        yo[0] = tanh_nc(py[0]);
        yo[4] = tanh_nc(py[4]);
        yo[8] = tanh_nc(py[8]);
    } else if (sub == 1) {
        yo[1] = tanh_nc(py[1]);
        yo[5] = tanh_nc(py[5]);
    } else if (sub == 2) {
        yo[2] = tanh_nc(py[2]);
        yo[6] = tanh_nc(py[6]);
    } else {
        yo[3] = tanh_nc(py[3]);
        yo[7] = tanh_nc(py[7]);
    }
}

extern "C" void kernel_launch(void* const* d_in, const int* in_sizes, int n_in,
                              void* d_out, int out_size, void* d_ws, size_t ws_size,
                              hipStream_t stream) {
    const float* input    = (const float*)d_in[0];  // (B,N,9,1)
    const float* w_pre    = (const float*)d_in[1];  // (9,4)
    const float* w_lstm   = (const float*)d_in[2];  // (4,16)
    const float* w_post   = (const float*)d_in[3];  // (16,9)
    const float* old_h    = (const float*)d_in[4];  // (B,N,16)
    const float* old_cell = (const float*)d_in[5];  // (B,N,16)

    float* out = (float*)d_out;
    float* yp       = out;                                    // B*N*9
    float* new_h    = out + (size_t)NNODES * OUT_DIM;         // B*N*16
    float* new_cell = new_h + (size_t)NNODES * CELLS;         // B*N*16

    dim3 grid(NBLK), block(TPB);
    distana_quad_kernel<<<grid, block, 0, stream>>>(
        input, w_pre, w_lstm, w_post, old_h, old_cell, yp, new_h, new_cell);
}

// Round 12
// 30.811 us; speedup vs baseline: 1.1380x; 1.0247x over previous
//
#include <hip/hip_runtime.h>
#include <math.h>

// DISTANA fused prediction-kernel step.
// B=128, N=4096, IN=9, PRE=4, CELLS=16, OUT=9.
// Outputs: y (B,N,9) | new_h (B,N,16) | new_cell (B,N,16), f32 concat.
//
// R12 = R11 (quad-cooperative, DPP butterflies, strided x/y lanes, 31.4us)
// with SINGLE-WAVE blocks: TPB=64, grid 32768. __launch_bounds__(64) lets
// the compiler elide s_barrier (workgroup == wave), and each wave becomes an
// independently dispatched/retired unit -> finest TLP granularity, no
// cross-wave staging sync, no block-level retirement coupling.
// Weights re-staged per block (976B; L2-resident after first generation).

#define NNODES 524288
#define IN_DIM 9
#define CELLS 16
#define OUT_DIM 9
#define TPB 64
#define NPB 16               // nodes per block (4 lanes/node, 64 threads)
#define NBLK (NNODES / NPB)  // 32768, divisible by 8
#define NXCD 8

typedef float f32x4 __attribute__((ext_vector_type(4)));

__device__ __forceinline__ float fast_rcp(float x) {
    return __builtin_amdgcn_rcpf(x);
}

__device__ __forceinline__ float tanh_nc(float x) {
    // no clamp: caller guarantees |x| << 44 (exp argument < 88, no overflow)
    float e = __expf(2.f * x);
    return (e - 1.f) * fast_rcp(e + 1.f);
}

__device__ __forceinline__ float fast_tanh(float x) {
    return tanh_nc(fminf(fmaxf(x, -15.f), 15.f));
}

// quad butterfly sum via DPP quad_perm: xor1 = [1,0,3,2] = 0xB1,
// xor2 = [2,3,0,1] = 0x4E. Pure VALU (mov_dpp + add), no LDS pipe.
__device__ __forceinline__ float qsum(float v) {
    int a = __builtin_amdgcn_update_dpp(0, __float_as_int(v), 0xB1, 0xF, 0xF, true);
    v += __int_as_float(a);
    int b = __builtin_amdgcn_update_dpp(0, __float_as_int(v), 0x4E, 0xF, 0xF, true);
    v += __int_as_float(b);
    return v;
}

__global__ __launch_bounds__(TPB) void distana_quad_kernel(
    const float* __restrict__ input,      // (B,N,9)
    const float* __restrict__ w_pre,      // (9,4)
    const float* __restrict__ w_lstm,     // (4,16)
    const float* __restrict__ w_post,     // (16,9)
    const float* __restrict__ old_h,      // (B,N,16)
    const float* __restrict__ old_cell,   // (B,N,16)
    float* __restrict__ y,                // (B,N,9)
    float* __restrict__ new_h,            // (B,N,16)
    float* __restrict__ new_cell)         // (B,N,16)
{
    __shared__ float sWpre[36];   // (9,4)
    __shared__ float sWl[64];     // (4,16)
    __shared__ float sWp[144];    // (16,9)

    const int t   = threadIdx.x;  // 0..63, one wave
    const int bid = blockIdx.x;
    // bijective XCD swizzle: contiguous tile range per XCD (32768 % 8 == 0)
    const int swz  = (bid & (NXCD - 1)) * (NBLK / NXCD) + (bid >> 3);
    const int node = swz * NPB + (t >> 2);
    const int sub  = t & 3;

    // ---- weight staging (64 lanes): 976B, L2-hot after first generation ----
    if (t < 36) sWpre[t] = w_pre[t];
    sWl[t] = w_lstm[t];
    sWp[t]      = w_post[t];
    sWp[t + 64] = w_post[t + 64];
    if (t < 16) sWp[t + 128] = w_post[t + 128];

    // ---- x first (deepest dependency): strided lane ownership, 3 loads ----
    const float* xp = input + (size_t)node * IN_DIM;
    float x0 = xp[sub];
    float x1 = xp[sub + 4];
    float x2 = (sub == 0) ? xp[8] : 0.f;

    const float* hp = old_h    + (size_t)node * CELLS + sub * 4;
    const float* cp = old_cell + (size_t)node * CELLS + sub * 4;
    f32x4 h = *(const f32x4*)hp;          // wave: 16 nodes x 64B contiguous
    f32x4 c = *(const f32x4*)cp;

    __syncthreads();   // workgroup == wave: compiles to waitcnt only, no s_barrier

    // ---- pre = tanh(x @ W_pre): 3-row partial dot + DPP butterfly ----
    float pre[4];
    #pragma unroll
    for (int p = 0; p < 4; ++p) {
        float s = x0 * sWpre[sub * 4 + p];
        s = fmaf(x1, sWpre[(sub + 4) * 4 + p], s);
        s = fmaf(x2, sWpre[32 + p], s);   // row 8 (x2==0 for sub!=0)
        pre[p] = fast_tanh(qsum(s));      // x unbounded -> keep clamp
    }

    // ---- CIFG cell: this lane owns cells sub*4 .. sub*4+3 ----
    // net = oh + pre.w: |oh|<~6, |pre.w|<=1 -> |net|<=7, exp safe unclamped
    f32x4 nh, nc;
    #pragma unroll
    for (int j = 0; j < 4; ++j) {
        const int cc = sub * 4 + j;
        float s = h[j];
        #pragma unroll
        for (int p = 0; p < 4; ++p)
            s = fmaf(pre[p], sWl[p * CELLS + cc], s);
        float e  = __expf(s);                 // e^net
        float e2 = e * e;                     // e^{2 net}
        float a  = 1.f + e;
        float b  = 1.f + e2;
        float r  = fast_rcp(a * b);           // one rcp for both gates
        float ig = e * b * r;                 // sigmoid(net)
        float g  = (e2 - 1.f) * a * r;        // tanh(net)
        float v  = fmaf(ig, g - c[j], c[j]);  // (1-i)*oc + i*g
        nc[j] = v;
        nh[j] = tanh_nc(v);                   // |v| <= max(|oc|,1) <= ~6
    }
    *(f32x4*)(new_h    + (size_t)node * CELLS + sub * 4) = nh;
    *(f32x4*)(new_cell + (size_t)node * CELLS + sub * 4) = nc;

    // ---- y = tanh(new_h @ W_post): partial over own 4 cells + butterfly ----
    float py[OUT_DIM];
    #pragma unroll
    for (int o = 0; o < OUT_DIM; ++o) {
        float s = 0.f;
        #pragma unroll
        for (int j = 0; j < 4; ++j)
            s = fmaf(nh[j], sWp[(sub * 4 + j) * OUT_DIM + o], s);
        py[o] = qsum(s);                  // |y pre-act| <= 16*0.25 = 4
    }
    // balanced 3/2/2/2 store, constant indices (no runtime-indexed arrays)
    float* yo = y + (size_t)node * OUT_DIM;
    if (sub == 0) {
        yo[0] = tanh_nc(py[0]);
        yo[4] = tanh_nc(py[4]);
        yo[8] = tanh_nc(py[8]);
    } else if (sub == 1) {
        yo[1] = tanh_nc(py[1]);
        yo[5] = tanh_nc(py[5]);
    } else if (sub == 2) {
        yo[2] = tanh_nc(py[2]);
        yo[6] = tanh_nc(py[6]);
    } else {
        yo[3] = tanh_nc(py[3]);
        yo[7] = tanh_nc(py[7]);
    }
}

extern "C" void kernel_launch(void* const* d_in, const int* in_sizes, int n_in,
                              void* d_out, int out_size, void* d_ws, size_t ws_size,
                              hipStream_t stream) {
    const float* input    = (const float*)d_in[0];  // (B,N,9,1)
    const float* w_pre    = (const float*)d_in[1];  // (9,4)
    const float* w_lstm   = (const float*)d_in[2];  // (4,16)
    const float* w_post   = (const float*)d_in[3];  // (16,9)
    const float* old_h    = (const float*)d_in[4];  // (B,N,16)
    const float* old_cell = (const float*)d_in[5];  // (B,N,16)

    float* out = (float*)d_out;
    float* yp       = out;                                    // B*N*9
    float* new_h    = out + (size_t)NNODES * OUT_DIM;         // B*N*16
    float* new_cell = new_h + (size_t)NNODES * CELLS;         // B*N*16

    dim3 grid(NBLK), block(TPB);
    distana_quad_kernel<<<grid, block, 0, stream>>>(
        input, w_pre, w_lstm, w_post, old_h, old_cell, yp, new_h, new_cell);
}